// Round 15
// baseline (604.832 us; speedup 1.0000x reference)
//
#include <hip/hip_runtime.h>
#include <hip/hip_bf16.h>

// Problem constants
#define BB   4
#define SS   2048
#define DDIM 512
#define HH   8
#define DHD  64
#define FFD  2048
#define LLN  4
#define NQKV 1536
#define BN_INV 0.9995003747f                 // 1/sqrt(1+1e-3)
#define QSCALE 0.18033688011112042f          // 0.125 * log2(e): softmax in exp2 domain

typedef __bf16 bf16x8 __attribute__((ext_vector_type(8)));
typedef __bf16 bf16x4 __attribute__((ext_vector_type(4)));
typedef float  f32x4  __attribute__((ext_vector_type(4)));
typedef float  f32x16 __attribute__((ext_vector_type(16)));

__device__ __forceinline__ void gl2lds16(const void* g, void* l) {
  __builtin_amdgcn_global_load_lds((const __attribute__((address_space(1))) void*)g,
                                   (__attribute__((address_space(3))) void*)l, 16, 0, 0);
}

__device__ __forceinline__ unsigned pkbf16(float a, float b) {
  union { __bf16 h[2]; unsigned u; } x;
  x.h[0] = (__bf16)a; x.h[1] = (__bf16)b;
  return x.u;
}

#define SBAR() do { __builtin_amdgcn_s_barrier(); asm volatile("" ::: "memory"); } while (0)

// bijective XCD swizzle (requires nwg % 8 == 0; true for all grids here)
__device__ __forceinline__ int2 xcd_swz(void) {
  const int f = blockIdx.y * gridDim.x + blockIdx.x;
  const int q = (gridDim.x * gridDim.y) >> 3;
  const int L = (f & 7) * q + (f >> 3);
  int2 r; r.x = L % gridDim.x; r.y = L / gridDim.x;
  return r;
}

// ---------- merged transpose for the four 512x512 weight sets ----------
__global__ __launch_bounds__(256) void k_transpose_w4(const float* __restrict__ wq,
                                                      const float* __restrict__ wk,
                                                      const float* __restrict__ wv,
                                                      const float* __restrict__ wo,
                                                      __bf16* __restrict__ wqkvt,
                                                      __bf16* __restrict__ wot) {
  __shared__ float tile[32][33];
  const int z = blockIdx.z, widx = z >> 2, layer = z & 3;
  const float* in = (widx == 0) ? wq : (widx == 1) ? wk : (widx == 2) ? wv : wo;
  in += (size_t)layer * DDIM * DDIM;
  __bf16* out = (widx < 3)
      ? wqkvt + (size_t)layer * NQKV * DDIM + (size_t)widx * DDIM * DDIM
      : wot + (size_t)layer * DDIM * DDIM;
  const int c0 = blockIdx.x * 32, r0 = blockIdx.y * 32;
  const int tx = threadIdx.x & 31, ty = threadIdx.x >> 5;
#pragma unroll
  for (int k = 0; k < 4; ++k) {
    int r = ty + k * 8;
    tile[r][tx] = in[(size_t)(r0 + r) * DDIM + (c0 + tx)];
  }
  __syncthreads();
#pragma unroll
  for (int k = 0; k < 4; ++k) {
    int c = ty + k * 8;
    out[(size_t)(c0 + c) * DDIM + (r0 + tx)] = (__bf16)tile[tx][c];
  }
}

// ---------- f32 [R][C] -> bf16 [C][R], batched over blockIdx.z ----------
__global__ __launch_bounds__(256) void k_transpose_w(const float* __restrict__ in,
                                                     __bf16* __restrict__ out,
                                                     int R, int C,
                                                     size_t in_zs, size_t out_zs) {
  __shared__ float tile[32][33];
  in += (size_t)blockIdx.z * in_zs;
  out += (size_t)blockIdx.z * out_zs;
  const int c0 = blockIdx.x * 32, r0 = blockIdx.y * 32;
  const int tx = threadIdx.x & 31, ty = threadIdx.x >> 5;
#pragma unroll
  for (int k = 0; k < 4; ++k) {
    int r = ty + k * 8;
    tile[r][tx] = in[(size_t)(r0 + r) * C + (c0 + tx)];
  }
  __syncthreads();
#pragma unroll
  for (int k = 0; k < 4; ++k) {
    int c = ty + k * 8;
    out[(size_t)(c0 + c) * R + (r0 + tx)] = (__bf16)tile[tx][c];
  }
}

// ---------- fused bias [L][1536] = concat(bq, bk, bv) ----------
__global__ __launch_bounds__(256) void k_bias_fuse(const float* __restrict__ bq,
                                                   const float* __restrict__ bk,
                                                   const float* __restrict__ bv,
                                                   float* __restrict__ out) {
  const int i = blockIdx.x * 256 + threadIdx.x;
  const int l = i / NQKV, j = i - l * NQKV;
  float v = (j < 512) ? bq[l * 512 + j]
          : (j < 1024) ? bk[l * 512 + j - 512]
                       : bv[l * 512 + j - 1024];
  out[i] = v;
}

// ---------- qkv [B][S][1536] (V slice) -> vt [B*H][DH][S] ----------
__global__ __launch_bounds__(256) void k_transpose_v(const __bf16* __restrict__ qkv,
                                                     __bf16* __restrict__ vt) {
  __shared__ __bf16 tile[32][33];
  const int s0 = blockIdx.x * 32;
  const int d0 = blockIdx.y * 32;
  const int bh = blockIdx.z, b = bh >> 3, h = bh & 7;
  const int tx = threadIdx.x & 31, ty = threadIdx.x >> 5;
#pragma unroll
  for (int k = 0; k < 4; ++k) {
    int s = ty + k * 8;
    tile[s][tx] = qkv[(size_t)(b * SS + s0 + s) * NQKV + 2 * DDIM + h * DHD + d0 + tx];
  }
  __syncthreads();
#pragma unroll
  for (int k = 0; k < 4; ++k) {
    int d = ty + k * 8;
    vt[(size_t)(bh * DHD + d0 + d) * SS + (s0 + tx)] = tile[tx][d];
  }
}

// ---------- seq f32 -> x f32 copy + xb bf16 ----------
__global__ __launch_bounds__(256) void k_cast(const float* __restrict__ in,
                                              float* __restrict__ xf,
                                              __bf16* __restrict__ xb) {
  const int i = (blockIdx.x * 256 + threadIdx.x) * 4;
  const float4 v = *(const float4*)(in + i);
  *(float4*)(xf + i) = v;
  bf16x4 o;
  o[0] = (__bf16)v.x; o[1] = (__bf16)v.y; o[2] = (__bf16)v.z; o[3] = (__bf16)v.w;
  *(bf16x4*)(xb + i) = o;
}

// ---------- GEMM 128x128 (2-phase dbuf) -- for N=512 shapes ----------
template <int EPI>
__global__ __launch_bounds__(256) void k_gemm_bt(const __bf16* __restrict__ A,
                                                 const __bf16* __restrict__ Bt,
                                                 const float* __restrict__ bias,
                                                 __bf16* __restrict__ Cb,
                                                 int M, int N, int K,
                                                 const float* __restrict__ xres,
                                                 float* __restrict__ xout,
                                                 const float* __restrict__ gvec,
                                                 const float* __restrict__ bvec) {
  __shared__ __align__(16) char As[2][16384];
  __shared__ __align__(16) char Bs[2][16384];
  const int tid = threadIdx.x;
  const int l = tid & 63, w = tid >> 6;
  const int wm = w >> 1, wn = w & 1;
  const int2 bxy = xcd_swz();
  const int m0 = bxy.y * 128, n0 = bxy.x * 128;
  const int lr = l & 15, lg = l >> 4;
  f32x4 acc[4][4] = {};
  const int nk = K >> 6;
  const size_t ldab = (size_t)K * 2;

  auto stage = [&](int buf, int kt) {
    const int k0b = kt * 128;
#pragma unroll
    for (int i = 0; i < 4; ++i) {
      const int chunk = i * 256 + tid;
      const int row = chunk >> 3;
      const int scb = ((chunk & 7) * 16) ^ ((row & 7) << 4);
      gl2lds16((const char*)A + (size_t)(m0 + row) * ldab + k0b + scb,
               As[buf] + (i * 256 + w * 64) * 16);
      gl2lds16((const char*)Bt + (size_t)(n0 + row) * ldab + k0b + scb,
               Bs[buf] + (i * 256 + w * 64) * 16);
    }
  };

  stage(0, 0);
  __syncthreads();
  int cur = 0;
  for (int kt = 0; kt < nk; ++kt) {
    if (kt + 1 < nk) stage(cur ^ 1, kt + 1);
#pragma unroll
    for (int kk = 0; kk < 2; ++kk) {
      bf16x8 a[4], b[4];
#pragma unroll
      for (int m = 0; m < 4; ++m) {
        const int row = wm * 64 + m * 16 + lr;
        const int cb = kk * 64 + lg * 16;
        a[m] = *(const bf16x8*)(As[cur] + row * 128 + (cb ^ ((row & 7) << 4)));
      }
#pragma unroll
      for (int n = 0; n < 4; ++n) {
        const int row = wn * 64 + n * 16 + lr;
        const int cb = kk * 64 + lg * 16;
        b[n] = *(const bf16x8*)(Bs[cur] + row * 128 + (cb ^ ((row & 7) << 4)));
      }
#pragma unroll
      for (int m = 0; m < 4; ++m)
#pragma unroll
        for (int n = 0; n < 4; ++n)
          acc[m][n] = __builtin_amdgcn_mfma_f32_16x16x32_bf16(a[m], b[n], acc[m][n], 0, 0, 0);
    }
    asm volatile("s_waitcnt vmcnt(0)" ::: "memory");
    __syncthreads();
    cur ^= 1;
  }
#pragma unroll
  for (int m = 0; m < 4; ++m) {
    const int gm = m0 + wm * 64 + m * 16 + lg * 4;
#pragma unroll
    for (int n = 0; n < 4; ++n) {
      const int gn = n0 + wn * 64 + n * 16 + lr;
      const float bv_ = bias[gn];
#pragma unroll
      for (int j = 0; j < 4; ++j) {
        const size_t idx = (size_t)(gm + j) * N + gn;
        float v = acc[m][n][j] + bv_;
        if constexpr (EPI == 1) {
          Cb[idx] = (__bf16)fmaxf(v, 0.0f);
        } else {  // EPI == 2
          float t = (xres[idx] + v) * BN_INV * gvec[gn] + bvec[gn];
          xout[idx] = t;
          Cb[idx] = (__bf16)t;
        }
      }
    }
  }
}

// ---------- GEMM 256x256, 8 waves, 4-phase interleave ----------
template <int EPI>
__global__ __launch_bounds__(512, 1) void k_gemm256(const __bf16* __restrict__ A,
                                                    const __bf16* __restrict__ Bt,
                                                    const float* __restrict__ bias,
                                                    __bf16* __restrict__ Cb,
                                                    int M, int N, int K) {
  __shared__ __align__(16) char As[2][32768];
  __shared__ __align__(16) char Bs[2][32768];
  const int tid = threadIdx.x;
  const int l = tid & 63, w = tid >> 6;
  const int wm = w >> 2, wn = w & 3;
  const int2 bxy = xcd_swz();
  const int m0 = bxy.y * 256, n0 = bxy.x * 256;
  const int lr = l & 15, lg = l >> 4;
  f32x4 acc[8][4] = {};
  const int nk = K >> 6;
  const size_t ldab = (size_t)K * 2;

  auto stA = [&](int buf, int kt, int h) {
    const int k0b = kt * 128;
#pragma unroll
    for (int i = 0; i < 2; ++i) {
      const int chunk = h * 1024 + i * 512 + tid;
      const int row = chunk >> 3;
      const int scb = ((chunk & 7) * 16) ^ ((row & 7) << 4);
      gl2lds16((const char*)A + (size_t)(m0 + row) * ldab + k0b + scb,
               As[buf] + (h * 1024 + i * 512 + w * 64) * 16);
    }
  };
  auto stB = [&](int buf, int kt, int h) {
    const int k0b = kt * 128;
#pragma unroll
    for (int i = 0; i < 2; ++i) {
      const int chunk = h * 1024 + i * 512 + tid;
      const int row = chunk >> 3;
      const int scb = ((chunk & 7) * 16) ^ ((row & 7) << 4);
      gl2lds16((const char*)Bt + (size_t)(n0 + row) * ldab + k0b + scb,
               Bs[buf] + (h * 1024 + i * 512 + w * 64) * 16);
    }
  };

  stA(0, 0, 0); stA(0, 0, 1); stB(0, 0, 0); stB(0, 0, 1);
  asm volatile("s_waitcnt vmcnt(0)" ::: "memory");
  SBAR();

  int cur = 0;
  for (int kt = 0; kt < nk; ++kt) {
    const char* Ac = As[cur];
    const char* Bc = Bs[cur];
    const int oth = cur ^ 1;
    const bool pf = (kt + 1 < nk);
    bf16x8 af[4][2], bfr[4][2];
#pragma unroll
    for (int mi = 0; mi < 4; ++mi) {
      const int row = wm * 128 + mi * 16 + lr;
      const int swz = (row & 7) << 4;
#pragma unroll
      for (int kk = 0; kk < 2; ++kk)
        af[mi][kk] = *(const bf16x8*)(Ac + row * 128 + ((kk * 64 + lg * 16) ^ swz));
    }
#pragma unroll
    for (int ni = 0; ni < 2; ++ni) {
      const int row = wn * 64 + ni * 16 + lr;
      const int swz = (row & 7) << 4;
#pragma unroll
      for (int kk = 0; kk < 2; ++kk)
        bfr[ni][kk] = *(const bf16x8*)(Bc + row * 128 + ((kk * 64 + lg * 16) ^ swz));
    }
    if (pf) { stA(oth, kt + 1, 0); stA(oth, kt + 1, 1); }
    SBAR();
    __builtin_amdgcn_s_setprio(1);
#pragma unroll
    for (int mi = 0; mi < 4; ++mi)
#pragma unroll
      for (int ni = 0; ni < 2; ++ni)
#pragma unroll
        for (int kk = 0; kk < 2; ++kk)
          acc[mi][ni] = __builtin_amdgcn_mfma_f32_16x16x32_bf16(af[mi][kk], bfr[ni][kk], acc[mi][ni], 0, 0, 0);
    __builtin_amdgcn_s_setprio(0);
    SBAR();
#pragma unroll
    for (int ni = 2; ni < 4; ++ni) {
      const int row = wn * 64 + ni * 16 + lr;
      const int swz = (row & 7) << 4;
#pragma unroll
      for (int kk = 0; kk < 2; ++kk)
        bfr[ni][kk] = *(const bf16x8*)(Bc + row * 128 + ((kk * 64 + lg * 16) ^ swz));
    }
    if (pf) { stB(oth, kt + 1, 0); stB(oth, kt + 1, 1); }
    SBAR();
    __builtin_amdgcn_s_setprio(1);
#pragma unroll
    for (int mi = 0; mi < 4; ++mi)
#pragma unroll
      for (int ni = 2; ni < 4; ++ni)
#pragma unroll
        for (int kk = 0; kk < 2; ++kk)
          acc[mi][ni] = __builtin_amdgcn_mfma_f32_16x16x32_bf16(af[mi][kk], bfr[ni][kk], acc[mi][ni], 0, 0, 0);
    __builtin_amdgcn_s_setprio(0);
    SBAR();
#pragma unroll
    for (int mi = 0; mi < 4; ++mi) {
      const int row = wm * 128 + (mi + 4) * 16 + lr;
      const int swz = (row & 7) << 4;
#pragma unroll
      for (int kk = 0; kk < 2; ++kk)
        af[mi][kk] = *(const bf16x8*)(Ac + row * 128 + ((kk * 64 + lg * 16) ^ swz));
    }
    SBAR();
    __builtin_amdgcn_s_setprio(1);
#pragma unroll
    for (int mi = 0; mi < 4; ++mi)
#pragma unroll
      for (int ni = 0; ni < 2; ++ni)
#pragma unroll
        for (int kk = 0; kk < 2; ++kk)
          acc[mi + 4][ni] = __builtin_amdgcn_mfma_f32_16x16x32_bf16(af[mi][kk], bfr[ni][kk], acc[mi + 4][ni], 0, 0, 0);
    __builtin_amdgcn_s_setprio(0);
    SBAR();
    __builtin_amdgcn_s_setprio(1);
#pragma unroll
    for (int mi = 0; mi < 4; ++mi)
#pragma unroll
      for (int ni = 2; ni < 4; ++ni)
#pragma unroll
        for (int kk = 0; kk < 2; ++kk)
          acc[mi + 4][ni] = __builtin_amdgcn_mfma_f32_16x16x32_bf16(af[mi][kk], bfr[ni][kk], acc[mi + 4][ni], 0, 0, 0);
    __builtin_amdgcn_s_setprio(0);
    asm volatile("s_waitcnt vmcnt(0)" ::: "memory");
    SBAR();
    cur ^= 1;
  }
#pragma unroll
  for (int mi = 0; mi < 8; ++mi) {
    const int gm = m0 + wm * 128 + mi * 16 + lg * 4;
#pragma unroll
    for (int ni = 0; ni < 4; ++ni) {
      const int gn = n0 + wn * 64 + ni * 16 + lr;
      const float bv_ = bias[gn];
#pragma unroll
      for (int j = 0; j < 4; ++j) {
        const size_t idx = (size_t)(gm + j) * N + gn;
        float v = acc[mi][ni][j] + bv_;
        if constexpr (EPI == 1) {
          Cb[idx] = (__bf16)fmaxf(v, 0.0f);
        } else {  // EPI == 3
          if (gn < DDIM) v *= QSCALE;
          Cb[idx] = (__bf16)v;
        }
      }
    }
  }
}

// ---------- Flash attention v8: v5 + 256B-line K layout ----------
// K tile stored as 64 lines x 256B (two kv-rows per line) with 4-bit XOR
// swizzle: byte(r,c16) = (r>>1)*256 + ((((r&1)<<3)+c16) ^ (r&15))*16.
// QK reads now spread 64 lanes over 16 slots (4/slot) -- the V-read pattern
// that measures conflict-free -- vs the old 8-slot/8-lane pattern (2.1M
// conflicts/dispatch). Stage keeps LINEAR LDS dest (gl2lds16 rule) and
// pre-swizzles the GLOBAL source (both-sides rule #21). Math unchanged.
__global__ __launch_bounds__(256, 2) void k_attn(const __bf16* __restrict__ QKV,
                                                 const __bf16* __restrict__ Vt,
                                                 __bf16* __restrict__ O) {
  __shared__ char smem[65536];
  const int tid = threadIdx.x, l = tid & 63, w = tid >> 6;
  const int lq = l & 31, hi = l >> 5;
  const int f = blockIdx.y * 16 + blockIdx.x;
  const int L = (f & 7) * 64 + (f >> 3);
  const int qt = L & 15, bh = L >> 4;
  const int b = bh >> 3, h = bh & 7;
  const int myq = qt * 128 + w * 32 + lq;
  bf16x8 qf[4];
  {
    const __bf16* qp = QKV + (size_t)(b * SS + myq) * NQKV + h * DHD + hi * 8;
#pragma unroll
    for (int kc = 0; kc < 4; ++kc)
      qf[kc] = *(const bf16x8*)(qp + kc * 16);
  }
  f32x16 oaccT[2] = {};
  float rsum = 0.f;

  auto stage = [&](int buf, int t) {
    const int kv0 = t * 128;
    char* Kd = smem + buf * 16384;
    char* Vd = smem + 32768 + buf * 16384;
    // K: decode linear chunk -> (line p, slot s) -> (lds row r, col c16),
    // then source = sigma(r) row at col c16 (pre-swizzled global address).
#pragma unroll
    for (int i = 0; i < 4; ++i) {
      const int chunk = i * 256 + tid;
      const int p = chunk >> 4, s = chunk & 15;
      const int r2 = p << 1;
      const int x = s ^ (r2 & 15);
      const int hb = x >> 3;                     // 0: even row, 1: odd row
      const int r = r2 + hb;
      const int c16 = (x ^ hb) & 7;
      const int rs = r ^ ((((r >> 2) + 1) & 2) * 6);  // sigma
      gl2lds16((const char*)QKV + ((size_t)(b * SS + kv0 + rs) * NQKV + DDIM + h * DHD) * 2 + c16 * 16,
               Kd + (i * 256 + w * 64) * 16);
    }
#pragma unroll
    for (int i = 0; i < 4; ++i) {
      const int chunk = i * 256 + tid;
      const int row = chunk >> 4;
      const int scb = ((chunk & 15) * 16) ^ ((row & 15) << 4);
      gl2lds16((const char*)Vt + ((size_t)(bh * DHD + row) * SS + kv0) * 2 + scb,
               Vd + (i * 256 + w * 64) * 16);
    }
  };

  stage(0, 0);
  __syncthreads();
  int cur = 0;
  for (int t = 0; t < SS / 128; ++t) {
    if (t < SS / 128 - 1) stage(cur ^ 1, t + 1);
    const char* Ks = smem + cur * 16384;
    const char* Vs = smem + 32768 + cur * 16384;
#pragma unroll
    for (int kt2 = 0; kt2 < 4; ++kt2) {
      const int krow = kt2 * 32 + lq;
      const int kline = krow >> 1;
      const int kbase = (krow & 1) << 3;
      const int kmask = krow & 15;
      f32x16 st = {};
      __builtin_amdgcn_s_setprio(1);
#pragma unroll
      for (int kc = 0; kc < 4; ++kc) {
        const int sl = (kbase + kc * 2 + hi) ^ kmask;
        bf16x8 kf = *(const bf16x8*)(Ks + kline * 256 + (sl << 4));
        st = __builtin_amdgcn_mfma_f32_32x32x16_bf16(kf, qf[kc], st, 0, 0, 0);
      }
      __builtin_amdgcn_s_setprio(0);
      unsigned pk8[8];
#pragma unroll
      for (int i = 0; i < 8; ++i) {
        const float e0 = __builtin_amdgcn_exp2f(st[2 * i]);
        const float e1 = __builtin_amdgcn_exp2f(st[2 * i + 1]);
        rsum += e0 + e1;
        pk8[i] = pkbf16(e0, e1);
      }
      union { unsigned u[4]; bf16x8 v; } pf0, pf1;
#pragma unroll
      for (int i = 0; i < 4; ++i) { pf0.u[i] = pk8[i]; pf1.u[i] = pk8[4 + i]; }
      __builtin_amdgcn_s_setprio(1);
#pragma unroll
      for (int dt = 0; dt < 2; ++dt) {
        const int vrow = dt * 32 + lq;
        const int vswz = (vrow & 15) << 4;
        bf16x8 vf0 = *(const bf16x8*)(Vs + vrow * 256 + ((kt2 * 64 + hi * 16) ^ vswz));
        bf16x8 vf1 = *(const bf16x8*)(Vs + vrow * 256 + ((kt2 * 64 + 32 + hi * 16) ^ vswz));
        oaccT[dt] = __builtin_amdgcn_mfma_f32_32x32x16_bf16(vf0, pf0.v, oaccT[dt], 0, 0, 0);
        oaccT[dt] = __builtin_amdgcn_mfma_f32_32x32x16_bf16(vf1, pf1.v, oaccT[dt], 0, 0, 0);
      }
      __builtin_amdgcn_s_setprio(0);
    }
    asm volatile("s_waitcnt vmcnt(0)" ::: "memory");
    __syncthreads();
    cur ^= 1;
  }
  rsum += __shfl_xor(rsum, 32);
  const float inv = 1.0f / rsum;
  __bf16* op = O + (size_t)(b * SS + myq) * DDIM + h * DHD;
#pragma unroll
  for (int dt = 0; dt < 2; ++dt)
#pragma unroll
    for (int g = 0; g < 4; ++g) {
      const int d0 = dt * 32 + g * 8 + hi * 4;
      unsigned u0 = pkbf16(oaccT[dt][4 * g + 0] * inv, oaccT[dt][4 * g + 1] * inv);
      unsigned u1 = pkbf16(oaccT[dt][4 * g + 2] * inv, oaccT[dt][4 * g + 3] * inv);
      uint2 uu; uu.x = u0; uu.y = u1;
      *(uint2*)(op + d0) = uu;
    }
}

// ---------- workspace layout ----------
static constexpr size_t SZ_WQKVT = (size_t)LLN * NQKV * DDIM * 2;   // 6 MB
static constexpr size_t SZ_WOT   = (size_t)LLN * DDIM * DDIM * 2;   // 2 MB
static constexpr size_t SZ_WT_DF = (size_t)LLN * DDIM * FFD * 2;    // 8 MB
static constexpr size_t SZ_BQKV  = (size_t)LLN * NQKV * 4;          // 24 KB
static constexpr size_t SZ_X     = (size_t)BB * SS * DDIM * 4;      // 16 MB
static constexpr size_t SZ_ABF   = (size_t)BB * SS * DDIM * 2;      // 8 MB
static constexpr size_t SZ_QKV   = (size_t)BB * SS * NQKV * 2;      // 24 MB
static constexpr size_t OFF_WQKVT = 0;
static constexpr size_t OFF_WOT  = OFF_WQKVT + SZ_WQKVT;
static constexpr size_t OFF_W1T  = OFF_WOT + SZ_WOT;
static constexpr size_t OFF_W2T  = OFF_W1T + SZ_WT_DF;
static constexpr size_t OFF_BQKV = OFF_W2T + SZ_WT_DF;
static constexpr size_t OFF_X    = OFF_BQKV + SZ_BQKV;
static constexpr size_t OFF_XB   = OFF_X + SZ_X;
static constexpr size_t OFF_QKV  = OFF_XB + SZ_ABF;
static constexpr size_t OFF_VT   = OFF_QKV + SZ_QKV;
static constexpr size_t OFF_OB   = OFF_VT + SZ_ABF;
static constexpr size_t OFF_H1   = OFF_QKV;  // FFN hidden aliases qkv+vt (dead then)

extern "C" void kernel_launch(void* const* d_in, const int* in_sizes, int n_in,
                              void* d_out, int out_size, void* d_ws, size_t ws_size,
                              hipStream_t stream) {
  const float* seq = (const float*)d_in[0];
  const float* wq = (const float*)d_in[1];  const float* bq = (const float*)d_in[2];
  const float* wk = (const float*)d_in[3];  const float* bk = (const float*)d_in[4];
  const float* wv = (const float*)d_in[5];  const float* bv = (const float*)d_in[6];
  const float* wo = (const float*)d_in[7];  const float* bo = (const float*)d_in[8];
  const float* w1 = (const float*)d_in[9];  const float* b1 = (const float*)d_in[10];
  const float* w2 = (const float*)d_in[11]; const float* b2 = (const float*)d_in[12];
  const float* g1 = (const float*)d_in[13]; const float* be1 = (const float*)d_in[14];
  const float* g2 = (const float*)d_in[15]; const float* be2 = (const float*)d_in[16];

  char* ws = (char*)d_ws;
  __bf16* wqkvt = (__bf16*)(ws + OFF_WQKVT);
  __bf16* wot = (__bf16*)(ws + OFF_WOT);
  __bf16* w1t = (__bf16*)(ws + OFF_W1T);
  __bf16* w2t = (__bf16*)(ws + OFF_W2T);
  float*  bqkv = (float*)(ws + OFF_BQKV);
  float*  xf  = (float*)(ws + OFF_X);
  __bf16* xb  = (__bf16*)(ws + OFF_XB);
  __bf16* qkvb = (__bf16*)(ws + OFF_QKV);
  __bf16* vtb = (__bf16*)(ws + OFF_VT);
  __bf16* ob  = (__bf16*)(ws + OFF_OB);
  __bf16* h1  = (__bf16*)(ws + OFF_H1);

  const size_t zDF = (size_t)DDIM * FFD;
  k_transpose_w4<<<dim3(16, 16, 16), 256, 0, stream>>>(wq, wk, wv, wo, wqkvt, wot);
  k_transpose_w<<<dim3(64, 16, LLN), 256, 0, stream>>>(w1, w1t, DDIM, FFD, zDF, zDF);
  k_transpose_w<<<dim3(16, 64, LLN), 256, 0, stream>>>(w2, w2t, FFD, DDIM, zDF, zDF);
  k_bias_fuse<<<LLN * NQKV / 256, 256, 0, stream>>>(bq, bk, bv, bqkv);
  k_cast<<<4096, 256, 0, stream>>>(seq, xf, xb);

  const int M = BB * SS;  // 8192
  for (int i = 0; i < LLN; ++i) {
    k_gemm256<3><<<dim3(NQKV / 256, M / 256), 512, 0, stream>>>(
        xb, wqkvt + (size_t)i * NQKV * DDIM, bqkv + i * NQKV, qkvb, M, NQKV, DDIM);
    k_transpose_v<<<dim3(SS / 32, DHD / 32, BB * HH), 256, 0, stream>>>(qkvb, vtb);
    k_attn<<<dim3(SS / 128, BB * HH), 256, 0, stream>>>(qkvb, vtb, ob);
    k_gemm_bt<2><<<dim3(DDIM / 128, M / 128), 256, 0, stream>>>(
        ob, wot + (size_t)i * DDIM * DDIM, bo + i * DDIM, xb, M, DDIM, DDIM,
        xf, xf, g1 + i * DDIM, be1 + i * DDIM);
    k_gemm256<1><<<dim3(FFD / 256, M / 256), 512, 0, stream>>>(
        xb, w1t + (size_t)i * DDIM * FFD, b1 + i * FFD, h1, M, FFD, DDIM);
    k_gemm_bt<2><<<dim3(DDIM / 128, M / 128), 256, 0, stream>>>(
        h1, w2t + (size_t)i * DDIM * FFD, b2 + i * DDIM, xb, M, DDIM, FFD,
        xf, (i == LLN - 1) ? (float*)d_out : xf, g2 + i * DDIM, be2 + i * DDIM);
  }
  (void)in_sizes; (void)n_in; (void)out_size; (void)ws_size;
}

// Round 16
// 604.316 us; speedup vs baseline: 1.0009x; 1.0009x over previous
//
#include <hip/hip_runtime.h>
#include <hip/hip_bf16.h>

// Problem constants
#define BB   4
#define SS   2048
#define DDIM 512
#define HH   8
#define DHD  64
#define FFD  2048
#define LLN  4
#define NQKV 1536
#define BN_INV 0.9995003747f                 // 1/sqrt(1+1e-3)
#define QSCALE 0.18033688011112042f          // 0.125 * log2(e): softmax in exp2 domain

typedef __bf16 bf16x8 __attribute__((ext_vector_type(8)));
typedef __bf16 bf16x4 __attribute__((ext_vector_type(4)));
typedef float  f32x4  __attribute__((ext_vector_type(4)));
typedef float  f32x16 __attribute__((ext_vector_type(16)));

__device__ __forceinline__ void gl2lds16(const void* g, void* l) {
  __builtin_amdgcn_global_load_lds((const __attribute__((address_space(1))) void*)g,
                                   (__attribute__((address_space(3))) void*)l, 16, 0, 0);
}

__device__ __forceinline__ unsigned pkbf16(float a, float b) {
  union { __bf16 h[2]; unsigned u; } x;
  x.h[0] = (__bf16)a; x.h[1] = (__bf16)b;
  return x.u;
}

#define SBAR() do { __builtin_amdgcn_s_barrier(); asm volatile("" ::: "memory"); } while (0)

// bijective XCD swizzle (requires nwg % 8 == 0; true for all grids here)
__device__ __forceinline__ int2 xcd_swz(void) {
  const int f = blockIdx.y * gridDim.x + blockIdx.x;
  const int q = (gridDim.x * gridDim.y) >> 3;
  const int L = (f & 7) * q + (f >> 3);
  int2 r; r.x = L % gridDim.x; r.y = L / gridDim.x;
  return r;
}

// ---------- merged transpose for the four 512x512 weight sets ----------
__global__ __launch_bounds__(256) void k_transpose_w4(const float* __restrict__ wq,
                                                      const float* __restrict__ wk,
                                                      const float* __restrict__ wv,
                                                      const float* __restrict__ wo,
                                                      __bf16* __restrict__ wqkvt,
                                                      __bf16* __restrict__ wot) {
  __shared__ float tile[32][33];
  const int z = blockIdx.z, widx = z >> 2, layer = z & 3;
  const float* in = (widx == 0) ? wq : (widx == 1) ? wk : (widx == 2) ? wv : wo;
  in += (size_t)layer * DDIM * DDIM;
  __bf16* out = (widx < 3)
      ? wqkvt + (size_t)layer * NQKV * DDIM + (size_t)widx * DDIM * DDIM
      : wot + (size_t)layer * DDIM * DDIM;
  const int c0 = blockIdx.x * 32, r0 = blockIdx.y * 32;
  const int tx = threadIdx.x & 31, ty = threadIdx.x >> 5;
#pragma unroll
  for (int k = 0; k < 4; ++k) {
    int r = ty + k * 8;
    tile[r][tx] = in[(size_t)(r0 + r) * DDIM + (c0 + tx)];
  }
  __syncthreads();
#pragma unroll
  for (int k = 0; k < 4; ++k) {
    int c = ty + k * 8;
    out[(size_t)(c0 + c) * DDIM + (r0 + tx)] = (__bf16)tile[tx][c];
  }
}

// ---------- f32 [R][C] -> bf16 [C][R], batched over blockIdx.z ----------
__global__ __launch_bounds__(256) void k_transpose_w(const float* __restrict__ in,
                                                     __bf16* __restrict__ out,
                                                     int R, int C,
                                                     size_t in_zs, size_t out_zs) {
  __shared__ float tile[32][33];
  in += (size_t)blockIdx.z * in_zs;
  out += (size_t)blockIdx.z * out_zs;
  const int c0 = blockIdx.x * 32, r0 = blockIdx.y * 32;
  const int tx = threadIdx.x & 31, ty = threadIdx.x >> 5;
#pragma unroll
  for (int k = 0; k < 4; ++k) {
    int r = ty + k * 8;
    tile[r][tx] = in[(size_t)(r0 + r) * C + (c0 + tx)];
  }
  __syncthreads();
#pragma unroll
  for (int k = 0; k < 4; ++k) {
    int c = ty + k * 8;
    out[(size_t)(c0 + c) * R + (r0 + tx)] = (__bf16)tile[tx][c];
  }
}

// ---------- fused bias [L][1536] = concat(bq, bk, bv) ----------
__global__ __launch_bounds__(256) void k_bias_fuse(const float* __restrict__ bq,
                                                   const float* __restrict__ bk,
                                                   const float* __restrict__ bv,
                                                   float* __restrict__ out) {
  const int i = blockIdx.x * 256 + threadIdx.x;
  const int l = i / NQKV, j = i - l * NQKV;
  float v = (j < 512) ? bq[l * 512 + j]
          : (j < 1024) ? bk[l * 512 + j - 512]
                       : bv[l * 512 + j - 1024];
  out[i] = v;
}

// ---------- qkv [B][S][1536] (V slice) -> vt [B*H][DH][S] ----------
__global__ __launch_bounds__(256) void k_transpose_v(const __bf16* __restrict__ qkv,
                                                     __bf16* __restrict__ vt) {
  __shared__ __bf16 tile[32][33];
  const int s0 = blockIdx.x * 32;
  const int d0 = blockIdx.y * 32;
  const int bh = blockIdx.z, b = bh >> 3, h = bh & 7;
  const int tx = threadIdx.x & 31, ty = threadIdx.x >> 5;
#pragma unroll
  for (int k = 0; k < 4; ++k) {
    int s = ty + k * 8;
    tile[s][tx] = qkv[(size_t)(b * SS + s0 + s) * NQKV + 2 * DDIM + h * DHD + d0 + tx];
  }
  __syncthreads();
#pragma unroll
  for (int k = 0; k < 4; ++k) {
    int d = ty + k * 8;
    vt[(size_t)(bh * DHD + d0 + d) * SS + (s0 + tx)] = tile[tx][d];
  }
}

// ---------- seq f32 -> x f32 copy + xb bf16 ----------
__global__ __launch_bounds__(256) void k_cast(const float* __restrict__ in,
                                              float* __restrict__ xf,
                                              __bf16* __restrict__ xb) {
  const int i = (blockIdx.x * 256 + threadIdx.x) * 4;
  const float4 v = *(const float4*)(in + i);
  *(float4*)(xf + i) = v;
  bf16x4 o;
  o[0] = (__bf16)v.x; o[1] = (__bf16)v.y; o[2] = (__bf16)v.z; o[3] = (__bf16)v.w;
  *(bf16x4*)(xb + i) = o;
}

// ---------- GEMM 128x128 (2-phase dbuf) -- for N=512 shapes ----------
template <int EPI>
__global__ __launch_bounds__(256) void k_gemm_bt(const __bf16* __restrict__ A,
                                                 const __bf16* __restrict__ Bt,
                                                 const float* __restrict__ bias,
                                                 __bf16* __restrict__ Cb,
                                                 int M, int N, int K,
                                                 const float* __restrict__ xres,
                                                 float* __restrict__ xout,
                                                 const float* __restrict__ gvec,
                                                 const float* __restrict__ bvec) {
  __shared__ __align__(16) char As[2][16384];
  __shared__ __align__(16) char Bs[2][16384];
  const int tid = threadIdx.x;
  const int l = tid & 63, w = tid >> 6;
  const int wm = w >> 1, wn = w & 1;
  const int2 bxy = xcd_swz();
  const int m0 = bxy.y * 128, n0 = bxy.x * 128;
  const int lr = l & 15, lg = l >> 4;
  f32x4 acc[4][4] = {};
  const int nk = K >> 6;
  const size_t ldab = (size_t)K * 2;

  auto stage = [&](int buf, int kt) {
    const int k0b = kt * 128;
#pragma unroll
    for (int i = 0; i < 4; ++i) {
      const int chunk = i * 256 + tid;
      const int row = chunk >> 3;
      const int scb = ((chunk & 7) * 16) ^ ((row & 7) << 4);
      gl2lds16((const char*)A + (size_t)(m0 + row) * ldab + k0b + scb,
               As[buf] + (i * 256 + w * 64) * 16);
      gl2lds16((const char*)Bt + (size_t)(n0 + row) * ldab + k0b + scb,
               Bs[buf] + (i * 256 + w * 64) * 16);
    }
  };

  stage(0, 0);
  __syncthreads();
  int cur = 0;
  for (int kt = 0; kt < nk; ++kt) {
    if (kt + 1 < nk) stage(cur ^ 1, kt + 1);
#pragma unroll
    for (int kk = 0; kk < 2; ++kk) {
      bf16x8 a[4], b[4];
#pragma unroll
      for (int m = 0; m < 4; ++m) {
        const int row = wm * 64 + m * 16 + lr;
        const int cb = kk * 64 + lg * 16;
        a[m] = *(const bf16x8*)(As[cur] + row * 128 + (cb ^ ((row & 7) << 4)));
      }
#pragma unroll
      for (int n = 0; n < 4; ++n) {
        const int row = wn * 64 + n * 16 + lr;
        const int cb = kk * 64 + lg * 16;
        b[n] = *(const bf16x8*)(Bs[cur] + row * 128 + (cb ^ ((row & 7) << 4)));
      }
#pragma unroll
      for (int m = 0; m < 4; ++m)
#pragma unroll
        for (int n = 0; n < 4; ++n)
          acc[m][n] = __builtin_amdgcn_mfma_f32_16x16x32_bf16(a[m], b[n], acc[m][n], 0, 0, 0);
    }
    asm volatile("s_waitcnt vmcnt(0)" ::: "memory");
    __syncthreads();
    cur ^= 1;
  }
#pragma unroll
  for (int m = 0; m < 4; ++m) {
    const int gm = m0 + wm * 64 + m * 16 + lg * 4;
#pragma unroll
    for (int n = 0; n < 4; ++n) {
      const int gn = n0 + wn * 64 + n * 16 + lr;
      const float bv_ = bias[gn];
#pragma unroll
      for (int j = 0; j < 4; ++j) {
        const size_t idx = (size_t)(gm + j) * N + gn;
        float v = acc[m][n][j] + bv_;
        if constexpr (EPI == 1) {
          Cb[idx] = (__bf16)fmaxf(v, 0.0f);
        } else {  // EPI == 2
          float t = (xres[idx] + v) * BN_INV * gvec[gn] + bvec[gn];
          xout[idx] = t;
          Cb[idx] = (__bf16)t;
        }
      }
    }
  }
}

// ---------- GEMM 256x256, 8 waves, 4-phase + COUNTED vmcnt (T3+T4) ----------
// Half-tile split: A0=rows 0-127, A1=128-255 (same for B). Wave fragment rows
// remapped so P1 frags are in A0+B0 for ALL waves:
//   mrow(mi) = mi<4 ? wm*64+mi*16 : 128+wm*64+(mi-4)*16
//   bcol(ni) = ni<2 ? wn*32+ni*16 : 128+wn*32+(ni-2)*16
// Stage order per tile kt (into other buffer, for kt+1): P1:A0 P2:B0 P3:B1 P4:A1
// (2 loads/wave each). Per-wave load-queue accounting (oldest first):
//   end P4: [A0,B0,B1,A1](kt+1)=8 -> vmcnt(4) => A0,B0 landed -> P1 safe
//   end P1: [B1,A1](kt+1)+[A0](kt+2)=6 -> vmcnt(4) => B1 landed -> P2 safe
//   end P2: [A1](kt+1)+[A0,B0](kt+2)=6 -> vmcnt(4) => A1 landed -> P3 safe
// Main loop NEVER drains to 0 (m218 lever); tail peels to vmcnt(2)/vmcnt(0).
// Each wave waits its own loads + s_barrier => cross-wave visibility.
// Per-output accumulation order unchanged -> bitwise-identical C.
template <int EPI>
__global__ __launch_bounds__(512, 1) void k_gemm256(const __bf16* __restrict__ A,
                                                    const __bf16* __restrict__ Bt,
                                                    const float* __restrict__ bias,
                                                    __bf16* __restrict__ Cb,
                                                    int M, int N, int K) {
  __shared__ __align__(16) char As[2][32768];
  __shared__ __align__(16) char Bs[2][32768];
  const int tid = threadIdx.x;
  const int l = tid & 63, w = tid >> 6;
  const int wm = w >> 2, wn = w & 3;
  const int2 bxy = xcd_swz();
  const int m0 = bxy.y * 256, n0 = bxy.x * 256;
  const int lr = l & 15, lg = l >> 4;
  f32x4 acc[8][4] = {};
  const int nk = K >> 6;
  const size_t ldab = (size_t)K * 2;

  // stage one half-tile (h=0: rows 0-127, h=1: rows 128-255); 2 loads/thread
  auto stA = [&](int buf, int kt, int h) {
    const int k0b = kt * 128;
#pragma unroll
    for (int i = 0; i < 2; ++i) {
      const int chunk = h * 1024 + i * 512 + tid;
      const int row = chunk >> 3;
      const int scb = ((chunk & 7) * 16) ^ ((row & 7) << 4);
      gl2lds16((const char*)A + (size_t)(m0 + row) * ldab + k0b + scb,
               As[buf] + (h * 1024 + i * 512 + w * 64) * 16);
    }
  };
  auto stB = [&](int buf, int kt, int h) {
    const int k0b = kt * 128;
#pragma unroll
    for (int i = 0; i < 2; ++i) {
      const int chunk = h * 1024 + i * 512 + tid;
      const int row = chunk >> 3;
      const int scb = ((chunk & 7) * 16) ^ ((row & 7) << 4);
      gl2lds16((const char*)Bt + (size_t)(n0 + row) * ldab + k0b + scb,
               Bs[buf] + (h * 1024 + i * 512 + w * 64) * 16);
    }
  };

  // prologue: A0,B0,B1,A1 of tile 0; wait until A0,B0 landed (B1,A1 in flight)
  stA(0, 0, 0); stB(0, 0, 0); stB(0, 0, 1); stA(0, 0, 1);
  asm volatile("s_waitcnt vmcnt(4)" ::: "memory");
  SBAR();

  int cur = 0;
  for (int kt = 0; kt < nk; ++kt) {
    const char* Ac = As[cur];
    const char* Bc = Bs[cur];
    const int oth = cur ^ 1;
    const bool pf = (kt + 1 < nk);
    bf16x8 af[4][2], bfr[4][2];
    // ---- P1: read a0-3 (A0) + b0-1 (B0); stage A0(kt+1)
#pragma unroll
    for (int mi = 0; mi < 4; ++mi) {
      const int row = wm * 64 + mi * 16 + lr;
      const int swz = (row & 7) << 4;
#pragma unroll
      for (int kk = 0; kk < 2; ++kk)
        af[mi][kk] = *(const bf16x8*)(Ac + row * 128 + ((kk * 64 + lg * 16) ^ swz));
    }
#pragma unroll
    for (int ni = 0; ni < 2; ++ni) {
      const int row = wn * 32 + ni * 16 + lr;
      const int swz = (row & 7) << 4;
#pragma unroll
      for (int kk = 0; kk < 2; ++kk)
        bfr[ni][kk] = *(const bf16x8*)(Bc + row * 128 + ((kk * 64 + lg * 16) ^ swz));
    }
    if (pf) stA(oth, kt + 1, 0);
    SBAR();
    __builtin_amdgcn_s_setprio(1);
#pragma unroll
    for (int mi = 0; mi < 4; ++mi)
#pragma unroll
      for (int ni = 0; ni < 2; ++ni)
#pragma unroll
        for (int kk = 0; kk < 2; ++kk)
          acc[mi][ni] = __builtin_amdgcn_mfma_f32_16x16x32_bf16(af[mi][kk], bfr[ni][kk], acc[mi][ni], 0, 0, 0);
    __builtin_amdgcn_s_setprio(0);
    if (pf) { asm volatile("s_waitcnt vmcnt(4)" ::: "memory"); }
    else    { asm volatile("s_waitcnt vmcnt(2)" ::: "memory"); }
    SBAR();
    // ---- P2: read b2-3 (B1); stage B0(kt+1)
#pragma unroll
    for (int ni = 2; ni < 4; ++ni) {
      const int row = 128 + wn * 32 + (ni - 2) * 16 + lr;
      const int swz = (row & 7) << 4;
#pragma unroll
      for (int kk = 0; kk < 2; ++kk)
        bfr[ni][kk] = *(const bf16x8*)(Bc + row * 128 + ((kk * 64 + lg * 16) ^ swz));
    }
    if (pf) stB(oth, kt + 1, 0);
    SBAR();
    __builtin_amdgcn_s_setprio(1);
#pragma unroll
    for (int mi = 0; mi < 4; ++mi)
#pragma unroll
      for (int ni = 2; ni < 4; ++ni)
#pragma unroll
        for (int kk = 0; kk < 2; ++kk)
          acc[mi][ni] = __builtin_amdgcn_mfma_f32_16x16x32_bf16(af[mi][kk], bfr[ni][kk], acc[mi][ni], 0, 0, 0);
    __builtin_amdgcn_s_setprio(0);
    if (pf) { asm volatile("s_waitcnt vmcnt(4)" ::: "memory"); }
    else    { asm volatile("s_waitcnt vmcnt(0)" ::: "memory"); }
    SBAR();
    // ---- P3: read a4-7 (A1, overwrite af); stage B1(kt+1)
#pragma unroll
    for (int mi = 0; mi < 4; ++mi) {
      const int row = 128 + wm * 64 + mi * 16 + lr;
      const int swz = (row & 7) << 4;
#pragma unroll
      for (int kk = 0; kk < 2; ++kk)
        af[mi][kk] = *(const bf16x8*)(Ac + row * 128 + ((kk * 64 + lg * 16) ^ swz));
    }
    if (pf) stB(oth, kt + 1, 1);
    SBAR();
    __builtin_amdgcn_s_setprio(1);
#pragma unroll
    for (int mi = 0; mi < 4; ++mi)
#pragma unroll
      for (int ni = 0; ni < 2; ++ni)
#pragma unroll
        for (int kk = 0; kk < 2; ++kk)
          acc[mi + 4][ni] = __builtin_amdgcn_mfma_f32_16x16x32_bf16(af[mi][kk], bfr[ni][kk], acc[mi + 4][ni], 0, 0, 0);
    __builtin_amdgcn_s_setprio(0);
    SBAR();
    // ---- P4: stage A1(kt+1)
    if (pf) stA(oth, kt + 1, 1);
    SBAR();
    __builtin_amdgcn_s_setprio(1);
#pragma unroll
    for (int mi = 0; mi < 4; ++mi)
#pragma unroll
      for (int ni = 2; ni < 4; ++ni)
#pragma unroll
        for (int kk = 0; kk < 2; ++kk)
          acc[mi + 4][ni] = __builtin_amdgcn_mfma_f32_16x16x32_bf16(af[mi][kk], bfr[ni][kk], acc[mi + 4][ni], 0, 0, 0);
    __builtin_amdgcn_s_setprio(0);
    if (pf) { asm volatile("s_waitcnt vmcnt(4)" ::: "memory"); }
    SBAR();
    cur ^= 1;
  }
  // epilogue with the half-split row/col mapping
#pragma unroll
  for (int mi = 0; mi < 8; ++mi) {
    const int mrow = (mi < 4) ? (wm * 64 + mi * 16) : (128 + wm * 64 + (mi - 4) * 16);
    const int gm = m0 + mrow + lg * 4;
#pragma unroll
    for (int ni = 0; ni < 4; ++ni) {
      const int bcol = (ni < 2) ? (wn * 32 + ni * 16) : (128 + wn * 32 + (ni - 2) * 16);
      const int gn = n0 + bcol + lr;
      const float bv_ = bias[gn];
#pragma unroll
      for (int j = 0; j < 4; ++j) {
        const size_t idx = (size_t)(gm + j) * N + gn;
        float v = acc[mi][ni][j] + bv_;
        if constexpr (EPI == 1) {
          Cb[idx] = (__bf16)fmaxf(v, 0.0f);
        } else {  // EPI == 3
          if (gn < DDIM) v *= QSCALE;
          Cb[idx] = (__bf16)v;
        }
      }
    }
  }
}

// ---------- Flash attention v8 (conflict-free, 49.9 us) ----------
__global__ __launch_bounds__(256, 2) void k_attn(const __bf16* __restrict__ QKV,
                                                 const __bf16* __restrict__ Vt,
                                                 __bf16* __restrict__ O) {
  __shared__ char smem[65536];
  const int tid = threadIdx.x, l = tid & 63, w = tid >> 6;
  const int lq = l & 31, hi = l >> 5;
  const int f = blockIdx.y * 16 + blockIdx.x;
  const int L = (f & 7) * 64 + (f >> 3);
  const int qt = L & 15, bh = L >> 4;
  const int b = bh >> 3, h = bh & 7;
  const int myq = qt * 128 + w * 32 + lq;
  bf16x8 qf[4];
  {
    const __bf16* qp = QKV + (size_t)(b * SS + myq) * NQKV + h * DHD + hi * 8;
#pragma unroll
    for (int kc = 0; kc < 4; ++kc)
      qf[kc] = *(const bf16x8*)(qp + kc * 16);
  }
  f32x16 oaccT[2] = {};
  float rsum = 0.f;

  auto stage = [&](int buf, int t) {
    const int kv0 = t * 128;
    char* Kd = smem + buf * 16384;
    char* Vd = smem + 32768 + buf * 16384;
#pragma unroll
    for (int i = 0; i < 4; ++i) {
      const int chunk = i * 256 + tid;
      const int p = chunk >> 4, s = chunk & 15;
      const int r2 = p << 1;
      const int x = s ^ (r2 & 15);
      const int hb = x >> 3;
      const int r = r2 + hb;
      const int c16 = (x ^ hb) & 7;
      const int rs = r ^ ((((r >> 2) + 1) & 2) * 6);  // sigma
      gl2lds16((const char*)QKV + ((size_t)(b * SS + kv0 + rs) * NQKV + DDIM + h * DHD) * 2 + c16 * 16,
               Kd + (i * 256 + w * 64) * 16);
    }
#pragma unroll
    for (int i = 0; i < 4; ++i) {
      const int chunk = i * 256 + tid;
      const int row = chunk >> 4;
      const int scb = ((chunk & 15) * 16) ^ ((row & 15) << 4);
      gl2lds16((const char*)Vt + ((size_t)(bh * DHD + row) * SS + kv0) * 2 + scb,
               Vd + (i * 256 + w * 64) * 16);
    }
  };

  stage(0, 0);
  __syncthreads();
  int cur = 0;
  for (int t = 0; t < SS / 128; ++t) {
    if (t < SS / 128 - 1) stage(cur ^ 1, t + 1);
    const char* Ks = smem + cur * 16384;
    const char* Vs = smem + 32768 + cur * 16384;
#pragma unroll
    for (int kt2 = 0; kt2 < 4; ++kt2) {
      const int krow = kt2 * 32 + lq;
      const int kline = krow >> 1;
      const int kbase = (krow & 1) << 3;
      const int kmask = krow & 15;
      f32x16 st = {};
      __builtin_amdgcn_s_setprio(1);
#pragma unroll
      for (int kc = 0; kc < 4; ++kc) {
        const int sl = (kbase + kc * 2 + hi) ^ kmask;
        bf16x8 kf = *(const bf16x8*)(Ks + kline * 256 + (sl << 4));
        st = __builtin_amdgcn_mfma_f32_32x32x16_bf16(kf, qf[kc], st, 0, 0, 0);
      }
      __builtin_amdgcn_s_setprio(0);
      unsigned pk8[8];
#pragma unroll
      for (int i = 0; i < 8; ++i) {
        const float e0 = __builtin_amdgcn_exp2f(st[2 * i]);
        const float e1 = __builtin_amdgcn_exp2f(st[2 * i + 1]);
        rsum += e0 + e1;
        pk8[i] = pkbf16(e0, e1);
      }
      union { unsigned u[4]; bf16x8 v; } pf0, pf1;
#pragma unroll
      for (int i = 0; i < 4; ++i) { pf0.u[i] = pk8[i]; pf1.u[i] = pk8[4 + i]; }
      __builtin_amdgcn_s_setprio(1);
#pragma unroll
      for (int dt = 0; dt < 2; ++dt) {
        const int vrow = dt * 32 + lq;
        const int vswz = (vrow & 15) << 4;
        bf16x8 vf0 = *(const bf16x8*)(Vs + vrow * 256 + ((kt2 * 64 + hi * 16) ^ vswz));
        bf16x8 vf1 = *(const bf16x8*)(Vs + vrow * 256 + ((kt2 * 64 + 32 + hi * 16) ^ vswz));
        oaccT[dt] = __builtin_amdgcn_mfma_f32_32x32x16_bf16(vf0, pf0.v, oaccT[dt], 0, 0, 0);
        oaccT[dt] = __builtin_amdgcn_mfma_f32_32x32x16_bf16(vf1, pf1.v, oaccT[dt], 0, 0, 0);
      }
      __builtin_amdgcn_s_setprio(0);
    }
    asm volatile("s_waitcnt vmcnt(0)" ::: "memory");
    __syncthreads();
    cur ^= 1;
  }
  rsum += __shfl_xor(rsum, 32);
  const float inv = 1.0f / rsum;
  __bf16* op = O + (size_t)(b * SS + myq) * DDIM + h * DHD;
#pragma unroll
  for (int dt = 0; dt < 2; ++dt)
#pragma unroll
    for (int g = 0; g < 4; ++g) {
      const int d0 = dt * 32 + g * 8 + hi * 4;
      unsigned u0 = pkbf16(oaccT[dt][4 * g + 0] * inv, oaccT[dt][4 * g + 1] * inv);
      unsigned u1 = pkbf16(oaccT[dt][4 * g + 2] * inv, oaccT[dt][4 * g + 3] * inv);
      uint2 uu; uu.x = u0; uu.y = u1;
      *(uint2*)(op + d0) = uu;
    }
}

// ---------- workspace layout ----------
static constexpr size_t SZ_WQKVT = (size_t)LLN * NQKV * DDIM * 2;   // 6 MB
static constexpr size_t SZ_WOT   = (size_t)LLN * DDIM * DDIM * 2;   // 2 MB
static constexpr size_t SZ_WT_DF = (size_t)LLN * DDIM * FFD * 2;    // 8 MB
static constexpr size_t SZ_BQKV  = (size_t)LLN * NQKV * 4;          // 24 KB
static constexpr size_t SZ_X     = (size_t)BB * SS * DDIM * 4;      // 16 MB
static constexpr size_t SZ_ABF   = (size_t)BB * SS * DDIM * 2;      // 8 MB
static constexpr size_t SZ_QKV   = (size_t)BB * SS * NQKV * 2;      // 24 MB
static constexpr size_t OFF_WQKVT = 0;
static constexpr size_t OFF_WOT  = OFF_WQKVT + SZ_WQKVT;
static constexpr size_t OFF_W1T  = OFF_WOT + SZ_WOT;
static constexpr size_t OFF_W2T  = OFF_W1T + SZ_WT_DF;
static constexpr size_t OFF_BQKV = OFF_W2T + SZ_WT_DF;
static constexpr size_t OFF_X    = OFF_BQKV + SZ_BQKV;
static constexpr size_t OFF_XB   = OFF_X + SZ_X;
static constexpr size_t OFF_QKV  = OFF_XB + SZ_ABF;
static constexpr size_t OFF_VT   = OFF_QKV + SZ_QKV;
static constexpr size_t OFF_OB   = OFF_VT + SZ_ABF;
static constexpr size_t OFF_H1   = OFF_QKV;  // FFN hidden aliases qkv+vt (dead then)

extern "C" void kernel_launch(void* const* d_in, const int* in_sizes, int n_in,
                              void* d_out, int out_size, void* d_ws, size_t ws_size,
                              hipStream_t stream) {
  const float* seq = (const float*)d_in[0];
  const float* wq = (const float*)d_in[1];  const float* bq = (const float*)d_in[2];
  const float* wk = (const float*)d_in[3];  const float* bk = (const float*)d_in[4];
  const float* wv = (const float*)d_in[5];  const float* bv = (const float*)d_in[6];
  const float* wo = (const float*)d_in[7];  const float* bo = (const float*)d_in[8];
  const float* w1 = (const float*)d_in[9];  const float* b1 = (const float*)d_in[10];
  const float* w2 = (const float*)d_in[11]; const float* b2 = (const float*)d_in[12];
  const float* g1 = (const float*)d_in[13]; const float* be1 = (const float*)d_in[14];
  const float* g2 = (const float*)d_in[15]; const float* be2 = (const float*)d_in[16];

  char* ws = (char*)d_ws;
  __bf16* wqkvt = (__bf16*)(ws + OFF_WQKVT);
  __bf16* wot = (__bf16*)(ws + OFF_WOT);
  __bf16* w1t = (__bf16*)(ws + OFF_W1T);
  __bf16* w2t = (__bf16*)(ws + OFF_W2T);
  float*  bqkv = (float*)(ws + OFF_BQKV);
  float*  xf  = (float*)(ws + OFF_X);
  __bf16* xb  = (__bf16*)(ws + OFF_XB);
  __bf16* qkvb = (__bf16*)(ws + OFF_QKV);
  __bf16* vtb = (__bf16*)(ws + OFF_VT);
  __bf16* ob  = (__bf16*)(ws + OFF_OB);
  __bf16* h1  = (__bf16*)(ws + OFF_H1);

  const size_t zDF = (size_t)DDIM * FFD;
  k_transpose_w4<<<dim3(16, 16, 16), 256, 0, stream>>>(wq, wk, wv, wo, wqkvt, wot);
  k_transpose_w<<<dim3(64, 16, LLN), 256, 0, stream>>>(w1, w1t, DDIM, FFD, zDF, zDF);
  k_transpose_w<<<dim3(16, 64, LLN), 256, 0, stream>>>(w2, w2t, FFD, DDIM, zDF, zDF);
  k_bias_fuse<<<LLN * NQKV / 256, 256, 0, stream>>>(bq, bk, bv, bqkv);
  k_cast<<<4096, 256, 0, stream>>>(seq, xf, xb);

  const int M = BB * SS;  // 8192
  for (int i = 0; i < LLN; ++i) {
    k_gemm256<3><<<dim3(NQKV / 256, M / 256), 512, 0, stream>>>(
        xb, wqkvt + (size_t)i * NQKV * DDIM, bqkv + i * NQKV, qkvb, M, NQKV, DDIM);
    k_transpose_v<<<dim3(SS / 32, DHD / 32, BB * HH), 256, 0, stream>>>(qkvb, vtb);
    k_attn<<<dim3(SS / 128, BB * HH), 256, 0, stream>>>(qkvb, vtb, ob);
    k_gemm_bt<2><<<dim3(DDIM / 128, M / 128), 256, 0, stream>>>(
        ob, wot + (size_t)i * DDIM * DDIM, bo + i * DDIM, xb, M, DDIM, DDIM,
        xf, xf, g1 + i * DDIM, be1 + i * DDIM);
    k_gemm256<1><<<dim3(FFD / 256, M / 256), 512, 0, stream>>>(
        xb, w1t + (size_t)i * DDIM * FFD, b1 + i * FFD, h1, M, FFD, DDIM);
    k_gemm_bt<2><<<dim3(DDIM / 128, M / 128), 256, 0, stream>>>(
        h1, w2t + (size_t)i * DDIM * FFD, b2 + i * DDIM, xb, M, DDIM, FFD,
        xf, (i == LLN - 1) ? (float*)d_out : xf, g2 + i * DDIM, be2 + i * DDIM);
  }
  (void)in_sizes; (void)n_in; (void)out_size; (void)ws_size;
}

// Round 17
// 579.405 us; speedup vs baseline: 1.0439x; 1.0430x over previous
//
#include <hip/hip_runtime.h>
#include <hip/hip_bf16.h>

// Problem constants
#define BB   4
#define SS   2048
#define DDIM 512
#define HH   8
#define DHD  64
#define FFD  2048
#define LLN  4
#define NQKV 1536
#define BN_INV 0.9995003747f                 // 1/sqrt(1+1e-3)
#define QSCALE 0.18033688011112042f          // 0.125 * log2(e): softmax in exp2 domain

typedef __bf16 bf16x8 __attribute__((ext_vector_type(8)));
typedef __bf16 bf16x4 __attribute__((ext_vector_type(4)));
typedef float  f32x4  __attribute__((ext_vector_type(4)));
typedef float  f32x16 __attribute__((ext_vector_type(16)));

__device__ __forceinline__ void gl2lds16(const void* g, void* l) {
  __builtin_amdgcn_global_load_lds((const __attribute__((address_space(1))) void*)g,
                                   (__attribute__((address_space(3))) void*)l, 16, 0, 0);
}

__device__ __forceinline__ unsigned pkbf16(float a, float b) {
  union { __bf16 h[2]; unsigned u; } x;
  x.h[0] = (__bf16)a; x.h[1] = (__bf16)b;
  return x.u;
}

#define SBAR() do { __builtin_amdgcn_s_barrier(); asm volatile("" ::: "memory"); } while (0)

// bijective XCD swizzle (requires nwg % 8 == 0; true for all grids here)
__device__ __forceinline__ int2 xcd_swz(void) {
  const int f = blockIdx.y * gridDim.x + blockIdx.x;
  const int q = (gridDim.x * gridDim.y) >> 3;
  const int L = (f & 7) * q + (f >> 3);
  int2 r; r.x = L % gridDim.x; r.y = L / gridDim.x;
  return r;
}

// ---------- merged transpose for the four 512x512 weight sets ----------
__global__ __launch_bounds__(256) void k_transpose_w4(const float* __restrict__ wq,
                                                      const float* __restrict__ wk,
                                                      const float* __restrict__ wv,
                                                      const float* __restrict__ wo,
                                                      __bf16* __restrict__ wqkvt,
                                                      __bf16* __restrict__ wot) {
  __shared__ float tile[32][33];
  const int z = blockIdx.z, widx = z >> 2, layer = z & 3;
  const float* in = (widx == 0) ? wq : (widx == 1) ? wk : (widx == 2) ? wv : wo;
  in += (size_t)layer * DDIM * DDIM;
  __bf16* out = (widx < 3)
      ? wqkvt + (size_t)layer * NQKV * DDIM + (size_t)widx * DDIM * DDIM
      : wot + (size_t)layer * DDIM * DDIM;
  const int c0 = blockIdx.x * 32, r0 = blockIdx.y * 32;
  const int tx = threadIdx.x & 31, ty = threadIdx.x >> 5;
#pragma unroll
  for (int k = 0; k < 4; ++k) {
    int r = ty + k * 8;
    tile[r][tx] = in[(size_t)(r0 + r) * DDIM + (c0 + tx)];
  }
  __syncthreads();
#pragma unroll
  for (int k = 0; k < 4; ++k) {
    int c = ty + k * 8;
    out[(size_t)(c0 + c) * DDIM + (r0 + tx)] = (__bf16)tile[tx][c];
  }
}

// ---------- f32 [R][C] -> bf16 [C][R], batched over blockIdx.z ----------
__global__ __launch_bounds__(256) void k_transpose_w(const float* __restrict__ in,
                                                     __bf16* __restrict__ out,
                                                     int R, int C,
                                                     size_t in_zs, size_t out_zs) {
  __shared__ float tile[32][33];
  in += (size_t)blockIdx.z * in_zs;
  out += (size_t)blockIdx.z * out_zs;
  const int c0 = blockIdx.x * 32, r0 = blockIdx.y * 32;
  const int tx = threadIdx.x & 31, ty = threadIdx.x >> 5;
#pragma unroll
  for (int k = 0; k < 4; ++k) {
    int r = ty + k * 8;
    tile[r][tx] = in[(size_t)(r0 + r) * C + (c0 + tx)];
  }
  __syncthreads();
#pragma unroll
  for (int k = 0; k < 4; ++k) {
    int c = ty + k * 8;
    out[(size_t)(c0 + c) * R + (r0 + tx)] = (__bf16)tile[tx][c];
  }
}

// ---------- fused bias [L][1536] = concat(bq, bk, bv) ----------
__global__ __launch_bounds__(256) void k_bias_fuse(const float* __restrict__ bq,
                                                   const float* __restrict__ bk,
                                                   const float* __restrict__ bv,
                                                   float* __restrict__ out) {
  const int i = blockIdx.x * 256 + threadIdx.x;
  const int l = i / NQKV, j = i - l * NQKV;
  float v = (j < 512) ? bq[l * 512 + j]
          : (j < 1024) ? bk[l * 512 + j - 512]
                       : bv[l * 512 + j - 1024];
  out[i] = v;
}

// ---------- qkv [B][S][1536] (V slice) -> vt [B*H][DH][S] ----------
__global__ __launch_bounds__(256) void k_transpose_v(const __bf16* __restrict__ qkv,
                                                     __bf16* __restrict__ vt) {
  __shared__ __bf16 tile[32][33];
  const int s0 = blockIdx.x * 32;
  const int d0 = blockIdx.y * 32;
  const int bh = blockIdx.z, b = bh >> 3, h = bh & 7;
  const int tx = threadIdx.x & 31, ty = threadIdx.x >> 5;
#pragma unroll
  for (int k = 0; k < 4; ++k) {
    int s = ty + k * 8;
    tile[s][tx] = qkv[(size_t)(b * SS + s0 + s) * NQKV + 2 * DDIM + h * DHD + d0 + tx];
  }
  __syncthreads();
#pragma unroll
  for (int k = 0; k < 4; ++k) {
    int d = ty + k * 8;
    vt[(size_t)(bh * DHD + d0 + d) * SS + (s0 + tx)] = tile[tx][d];
  }
}

// ---------- seq f32 -> x f32 copy + xb bf16 ----------
__global__ __launch_bounds__(256) void k_cast(const float* __restrict__ in,
                                              float* __restrict__ xf,
                                              __bf16* __restrict__ xb) {
  const int i = (blockIdx.x * 256 + threadIdx.x) * 4;
  const float4 v = *(const float4*)(in + i);
  *(float4*)(xf + i) = v;
  bf16x4 o;
  o[0] = (__bf16)v.x; o[1] = (__bf16)v.y; o[2] = (__bf16)v.z; o[3] = (__bf16)v.w;
  *(bf16x4*)(xb + i) = o;
}

// ---------- GEMM 128x64 (2-phase dbuf), N=512 shapes ----------
// Smaller tile -> grid 512 blocks = 2 resident/CU (LDS 48KB, 3-block capacity):
// inter-block wave overlap (m114) hides the per-K-step drain that a 1-block/CU
// 128x128 grid (256 blocks) exposes. Accumulation order per output unchanged.
// EPI 1: Cb=relu(v); 2: t=(f32 xres + v)*BN_INV*g+be -> xout f32 + Cb bf16
template <int EPI>
__global__ __launch_bounds__(256, 3) void k_gemm_bt(const __bf16* __restrict__ A,
                                                    const __bf16* __restrict__ Bt,
                                                    const float* __restrict__ bias,
                                                    __bf16* __restrict__ Cb,
                                                    int M, int N, int K,
                                                    const float* __restrict__ xres,
                                                    float* __restrict__ xout,
                                                    const float* __restrict__ gvec,
                                                    const float* __restrict__ bvec) {
  __shared__ __align__(16) char As[2][16384];
  __shared__ __align__(16) char Bs[2][8192];
  const int tid = threadIdx.x;
  const int l = tid & 63, w = tid >> 6;
  const int wm = w >> 1, wn = w & 1;
  const int2 bxy = xcd_swz();
  const int m0 = bxy.y * 128, n0 = bxy.x * 64;
  const int lr = l & 15, lg = l >> 4;
  f32x4 acc[4][2] = {};
  const int nk = K >> 6;
  const size_t ldab = (size_t)K * 2;

  auto stage = [&](int buf, int kt) {
    const int k0b = kt * 128;
#pragma unroll
    for (int i = 0; i < 4; ++i) {
      const int chunk = i * 256 + tid;
      const int row = chunk >> 3;
      const int scb = ((chunk & 7) * 16) ^ ((row & 7) << 4);
      gl2lds16((const char*)A + (size_t)(m0 + row) * ldab + k0b + scb,
               As[buf] + (i * 256 + w * 64) * 16);
    }
#pragma unroll
    for (int i = 0; i < 2; ++i) {
      const int chunk = i * 256 + tid;
      const int row = chunk >> 3;
      const int scb = ((chunk & 7) * 16) ^ ((row & 7) << 4);
      gl2lds16((const char*)Bt + (size_t)(n0 + row) * ldab + k0b + scb,
               Bs[buf] + (i * 256 + w * 64) * 16);
    }
  };

  stage(0, 0);
  __syncthreads();
  int cur = 0;
  for (int kt = 0; kt < nk; ++kt) {
    if (kt + 1 < nk) stage(cur ^ 1, kt + 1);
#pragma unroll
    for (int kk = 0; kk < 2; ++kk) {
      bf16x8 a[4], b[2];
#pragma unroll
      for (int m = 0; m < 4; ++m) {
        const int row = wm * 64 + m * 16 + lr;
        const int cb = kk * 64 + lg * 16;
        a[m] = *(const bf16x8*)(As[cur] + row * 128 + (cb ^ ((row & 7) << 4)));
      }
#pragma unroll
      for (int n = 0; n < 2; ++n) {
        const int row = wn * 32 + n * 16 + lr;
        const int cb = kk * 64 + lg * 16;
        b[n] = *(const bf16x8*)(Bs[cur] + row * 128 + (cb ^ ((row & 7) << 4)));
      }
#pragma unroll
      for (int m = 0; m < 4; ++m)
#pragma unroll
        for (int n = 0; n < 2; ++n)
          acc[m][n] = __builtin_amdgcn_mfma_f32_16x16x32_bf16(a[m], b[n], acc[m][n], 0, 0, 0);
    }
    asm volatile("s_waitcnt vmcnt(0)" ::: "memory");
    __syncthreads();
    cur ^= 1;
  }
#pragma unroll
  for (int m = 0; m < 4; ++m) {
    const int gm = m0 + wm * 64 + m * 16 + lg * 4;
#pragma unroll
    for (int n = 0; n < 2; ++n) {
      const int gn = n0 + wn * 32 + n * 16 + lr;
      const float bv_ = bias[gn];
#pragma unroll
      for (int j = 0; j < 4; ++j) {
        const size_t idx = (size_t)(gm + j) * N + gn;
        float v = acc[m][n][j] + bv_;
        if constexpr (EPI == 1) {
          Cb[idx] = (__bf16)fmaxf(v, 0.0f);
        } else {  // EPI == 2
          float t = (xres[idx] + v) * BN_INV * gvec[gn] + bvec[gn];
          xout[idx] = t;
          Cb[idx] = (__bf16)t;
        }
      }
    }
  }
}

// ---------- GEMM 256x256, 8 waves, 4-phase + counted vmcnt (R16) ----------
template <int EPI>
__global__ __launch_bounds__(512, 1) void k_gemm256(const __bf16* __restrict__ A,
                                                    const __bf16* __restrict__ Bt,
                                                    const float* __restrict__ bias,
                                                    __bf16* __restrict__ Cb,
                                                    int M, int N, int K) {
  __shared__ __align__(16) char As[2][32768];
  __shared__ __align__(16) char Bs[2][32768];
  const int tid = threadIdx.x;
  const int l = tid & 63, w = tid >> 6;
  const int wm = w >> 2, wn = w & 3;
  const int2 bxy = xcd_swz();
  const int m0 = bxy.y * 256, n0 = bxy.x * 256;
  const int lr = l & 15, lg = l >> 4;
  f32x4 acc[8][4] = {};
  const int nk = K >> 6;
  const size_t ldab = (size_t)K * 2;

  auto stA = [&](int buf, int kt, int h) {
    const int k0b = kt * 128;
#pragma unroll
    for (int i = 0; i < 2; ++i) {
      const int chunk = h * 1024 + i * 512 + tid;
      const int row = chunk >> 3;
      const int scb = ((chunk & 7) * 16) ^ ((row & 7) << 4);
      gl2lds16((const char*)A + (size_t)(m0 + row) * ldab + k0b + scb,
               As[buf] + (h * 1024 + i * 512 + w * 64) * 16);
    }
  };
  auto stB = [&](int buf, int kt, int h) {
    const int k0b = kt * 128;
#pragma unroll
    for (int i = 0; i < 2; ++i) {
      const int chunk = h * 1024 + i * 512 + tid;
      const int row = chunk >> 3;
      const int scb = ((chunk & 7) * 16) ^ ((row & 7) << 4);
      gl2lds16((const char*)Bt + (size_t)(n0 + row) * ldab + k0b + scb,
               Bs[buf] + (h * 1024 + i * 512 + w * 64) * 16);
    }
  };

  stA(0, 0, 0); stB(0, 0, 0); stB(0, 0, 1); stA(0, 0, 1);
  asm volatile("s_waitcnt vmcnt(4)" ::: "memory");
  SBAR();

  int cur = 0;
  for (int kt = 0; kt < nk; ++kt) {
    const char* Ac = As[cur];
    const char* Bc = Bs[cur];
    const int oth = cur ^ 1;
    const bool pf = (kt + 1 < nk);
    bf16x8 af[4][2], bfr[4][2];
    // ---- P1: read a0-3 (A0) + b0-1 (B0); stage A0(kt+1)
#pragma unroll
    for (int mi = 0; mi < 4; ++mi) {
      const int row = wm * 64 + mi * 16 + lr;
      const int swz = (row & 7) << 4;
#pragma unroll
      for (int kk = 0; kk < 2; ++kk)
        af[mi][kk] = *(const bf16x8*)(Ac + row * 128 + ((kk * 64 + lg * 16) ^ swz));
    }
#pragma unroll
    for (int ni = 0; ni < 2; ++ni) {
      const int row = wn * 32 + ni * 16 + lr;
      const int swz = (row & 7) << 4;
#pragma unroll
      for (int kk = 0; kk < 2; ++kk)
        bfr[ni][kk] = *(const bf16x8*)(Bc + row * 128 + ((kk * 64 + lg * 16) ^ swz));
    }
    if (pf) stA(oth, kt + 1, 0);
    SBAR();
    __builtin_amdgcn_s_setprio(1);
#pragma unroll
    for (int mi = 0; mi < 4; ++mi)
#pragma unroll
      for (int ni = 0; ni < 2; ++ni)
#pragma unroll
        for (int kk = 0; kk < 2; ++kk)
          acc[mi][ni] = __builtin_amdgcn_mfma_f32_16x16x32_bf16(af[mi][kk], bfr[ni][kk], acc[mi][ni], 0, 0, 0);
    __builtin_amdgcn_s_setprio(0);
    if (pf) { asm volatile("s_waitcnt vmcnt(4)" ::: "memory"); }
    else    { asm volatile("s_waitcnt vmcnt(2)" ::: "memory"); }
    SBAR();
    // ---- P2: read b2-3 (B1); stage B0(kt+1)
#pragma unroll
    for (int ni = 2; ni < 4; ++ni) {
      const int row = 128 + wn * 32 + (ni - 2) * 16 + lr;
      const int swz = (row & 7) << 4;
#pragma unroll
      for (int kk = 0; kk < 2; ++kk)
        bfr[ni][kk] = *(const bf16x8*)(Bc + row * 128 + ((kk * 64 + lg * 16) ^ swz));
    }
    if (pf) stB(oth, kt + 1, 0);
    SBAR();
    __builtin_amdgcn_s_setprio(1);
#pragma unroll
    for (int mi = 0; mi < 4; ++mi)
#pragma unroll
      for (int ni = 2; ni < 4; ++ni)
#pragma unroll
        for (int kk = 0; kk < 2; ++kk)
          acc[mi][ni] = __builtin_amdgcn_mfma_f32_16x16x32_bf16(af[mi][kk], bfr[ni][kk], acc[mi][ni], 0, 0, 0);
    __builtin_amdgcn_s_setprio(0);
    if (pf) { asm volatile("s_waitcnt vmcnt(4)" ::: "memory"); }
    else    { asm volatile("s_waitcnt vmcnt(0)" ::: "memory"); }
    SBAR();
    // ---- P3: read a4-7 (A1); stage B1(kt+1)
#pragma unroll
    for (int mi = 0; mi < 4; ++mi) {
      const int row = 128 + wm * 64 + mi * 16 + lr;
      const int swz = (row & 7) << 4;
#pragma unroll
      for (int kk = 0; kk < 2; ++kk)
        af[mi][kk] = *(const bf16x8*)(Ac + row * 128 + ((kk * 64 + lg * 16) ^ swz));
    }
    if (pf) stB(oth, kt + 1, 1);
    SBAR();
    __builtin_amdgcn_s_setprio(1);
#pragma unroll
    for (int mi = 0; mi < 4; ++mi)
#pragma unroll
      for (int ni = 0; ni < 2; ++ni)
#pragma unroll
        for (int kk = 0; kk < 2; ++kk)
          acc[mi + 4][ni] = __builtin_amdgcn_mfma_f32_16x16x32_bf16(af[mi][kk], bfr[ni][kk], acc[mi + 4][ni], 0, 0, 0);
    __builtin_amdgcn_s_setprio(0);
    SBAR();
    // ---- P4: stage A1(kt+1)
    if (pf) stA(oth, kt + 1, 1);
    SBAR();
    __builtin_amdgcn_s_setprio(1);
#pragma unroll
    for (int mi = 0; mi < 4; ++mi)
#pragma unroll
      for (int ni = 2; ni < 4; ++ni)
#pragma unroll
        for (int kk = 0; kk < 2; ++kk)
          acc[mi + 4][ni] = __builtin_amdgcn_mfma_f32_16x16x32_bf16(af[mi][kk], bfr[ni][kk], acc[mi + 4][ni], 0, 0, 0);
    __builtin_amdgcn_s_setprio(0);
    if (pf) { asm volatile("s_waitcnt vmcnt(4)" ::: "memory"); }
    SBAR();
    cur ^= 1;
  }
#pragma unroll
  for (int mi = 0; mi < 8; ++mi) {
    const int mrow = (mi < 4) ? (wm * 64 + mi * 16) : (128 + wm * 64 + (mi - 4) * 16);
    const int gm = m0 + mrow + lg * 4;
#pragma unroll
    for (int ni = 0; ni < 4; ++ni) {
      const int bcol = (ni < 2) ? (wn * 32 + ni * 16) : (128 + wn * 32 + (ni - 2) * 16);
      const int gn = n0 + bcol + lr;
      const float bv_ = bias[gn];
#pragma unroll
      for (int j = 0; j < 4; ++j) {
        const size_t idx = (size_t)(gm + j) * N + gn;
        float v = acc[mi][ni][j] + bv_;
        if constexpr (EPI == 1) {
          Cb[idx] = (__bf16)fmaxf(v, 0.0f);
        } else {  // EPI == 3
          if (gn < DDIM) v *= QSCALE;
          Cb[idx] = (__bf16)v;
        }
      }
    }
  }
}

// ---------- Flash attention v8 (conflict-free, 49.9 us) ----------
__global__ __launch_bounds__(256, 2) void k_attn(const __bf16* __restrict__ QKV,
                                                 const __bf16* __restrict__ Vt,
                                                 __bf16* __restrict__ O) {
  __shared__ char smem[65536];
  const int tid = threadIdx.x, l = tid & 63, w = tid >> 6;
  const int lq = l & 31, hi = l >> 5;
  const int f = blockIdx.y * 16 + blockIdx.x;
  const int L = (f & 7) * 64 + (f >> 3);
  const int qt = L & 15, bh = L >> 4;
  const int b = bh >> 3, h = bh & 7;
  const int myq = qt * 128 + w * 32 + lq;
  bf16x8 qf[4];
  {
    const __bf16* qp = QKV + (size_t)(b * SS + myq) * NQKV + h * DHD + hi * 8;
#pragma unroll
    for (int kc = 0; kc < 4; ++kc)
      qf[kc] = *(const bf16x8*)(qp + kc * 16);
  }
  f32x16 oaccT[2] = {};
  float rsum = 0.f;

  auto stage = [&](int buf, int t) {
    const int kv0 = t * 128;
    char* Kd = smem + buf * 16384;
    char* Vd = smem + 32768 + buf * 16384;
#pragma unroll
    for (int i = 0; i < 4; ++i) {
      const int chunk = i * 256 + tid;
      const int p = chunk >> 4, s = chunk & 15;
      const int r2 = p << 1;
      const int x = s ^ (r2 & 15);
      const int hb = x >> 3;
      const int r = r2 + hb;
      const int c16 = (x ^ hb) & 7;
      const int rs = r ^ ((((r >> 2) + 1) & 2) * 6);  // sigma
      gl2lds16((const char*)QKV + ((size_t)(b * SS + kv0 + rs) * NQKV + DDIM + h * DHD) * 2 + c16 * 16,
               Kd + (i * 256 + w * 64) * 16);
    }
#pragma unroll
    for (int i = 0; i < 4; ++i) {
      const int chunk = i * 256 + tid;
      const int row = chunk >> 4;
      const int scb = ((chunk & 15) * 16) ^ ((row & 15) << 4);
      gl2lds16((const char*)Vt + ((size_t)(bh * DHD + row) * SS + kv0) * 2 + scb,
               Vd + (i * 256 + w * 64) * 16);
    }
  };

  stage(0, 0);
  __syncthreads();
  int cur = 0;
  for (int t = 0; t < SS / 128; ++t) {
    if (t < SS / 128 - 1) stage(cur ^ 1, t + 1);
    const char* Ks = smem + cur * 16384;
    const char* Vs = smem + 32768 + cur * 16384;
#pragma unroll
    for (int kt2 = 0; kt2 < 4; ++kt2) {
      const int krow = kt2 * 32 + lq;
      const int kline = krow >> 1;
      const int kbase = (krow & 1) << 3;
      const int kmask = krow & 15;
      f32x16 st = {};
      __builtin_amdgcn_s_setprio(1);
#pragma unroll
      for (int kc = 0; kc < 4; ++kc) {
        const int sl = (kbase + kc * 2 + hi) ^ kmask;
        bf16x8 kf = *(const bf16x8*)(Ks + kline * 256 + (sl << 4));
        st = __builtin_amdgcn_mfma_f32_32x32x16_bf16(kf, qf[kc], st, 0, 0, 0);
      }
      __builtin_amdgcn_s_setprio(0);
      unsigned pk8[8];
#pragma unroll
      for (int i = 0; i < 8; ++i) {
        const float e0 = __builtin_amdgcn_exp2f(st[2 * i]);
        const float e1 = __builtin_amdgcn_exp2f(st[2 * i + 1]);
        rsum += e0 + e1;
        pk8[i] = pkbf16(e0, e1);
      }
      union { unsigned u[4]; bf16x8 v; } pf0, pf1;
#pragma unroll
      for (int i = 0; i < 4; ++i) { pf0.u[i] = pk8[i]; pf1.u[i] = pk8[4 + i]; }
      __builtin_amdgcn_s_setprio(1);
#pragma unroll
      for (int dt = 0; dt < 2; ++dt) {
        const int vrow = dt * 32 + lq;
        const int vswz = (vrow & 15) << 4;
        bf16x8 vf0 = *(const bf16x8*)(Vs + vrow * 256 + ((kt2 * 64 + hi * 16) ^ vswz));
        bf16x8 vf1 = *(const bf16x8*)(Vs + vrow * 256 + ((kt2 * 64 + 32 + hi * 16) ^ vswz));
        oaccT[dt] = __builtin_amdgcn_mfma_f32_32x32x16_bf16(vf0, pf0.v, oaccT[dt], 0, 0, 0);
        oaccT[dt] = __builtin_amdgcn_mfma_f32_32x32x16_bf16(vf1, pf1.v, oaccT[dt], 0, 0, 0);
      }
      __builtin_amdgcn_s_setprio(0);
    }
    asm volatile("s_waitcnt vmcnt(0)" ::: "memory");
    __syncthreads();
    cur ^= 1;
  }
  rsum += __shfl_xor(rsum, 32);
  const float inv = 1.0f / rsum;
  __bf16* op = O + (size_t)(b * SS + myq) * DDIM + h * DHD;
#pragma unroll
  for (int dt = 0; dt < 2; ++dt)
#pragma unroll
    for (int g = 0; g < 4; ++g) {
      const int d0 = dt * 32 + g * 8 + hi * 4;
      unsigned u0 = pkbf16(oaccT[dt][4 * g + 0] * inv, oaccT[dt][4 * g + 1] * inv);
      unsigned u1 = pkbf16(oaccT[dt][4 * g + 2] * inv, oaccT[dt][4 * g + 3] * inv);
      uint2 uu; uu.x = u0; uu.y = u1;
      *(uint2*)(op + d0) = uu;
    }
}

// ---------- workspace layout ----------
static constexpr size_t SZ_WQKVT = (size_t)LLN * NQKV * DDIM * 2;   // 6 MB
static constexpr size_t SZ_WOT   = (size_t)LLN * DDIM * DDIM * 2;   // 2 MB
static constexpr size_t SZ_WT_DF = (size_t)LLN * DDIM * FFD * 2;    // 8 MB
static constexpr size_t SZ_BQKV  = (size_t)LLN * NQKV * 4;          // 24 KB
static constexpr size_t SZ_X     = (size_t)BB * SS * DDIM * 4;      // 16 MB
static constexpr size_t SZ_ABF   = (size_t)BB * SS * DDIM * 2;      // 8 MB
static constexpr size_t SZ_QKV   = (size_t)BB * SS * NQKV * 2;      // 24 MB
static constexpr size_t OFF_WQKVT = 0;
static constexpr size_t OFF_WOT  = OFF_WQKVT + SZ_WQKVT;
static constexpr size_t OFF_W1T  = OFF_WOT + SZ_WOT;
static constexpr size_t OFF_W2T  = OFF_W1T + SZ_WT_DF;
static constexpr size_t OFF_BQKV = OFF_W2T + SZ_WT_DF;
static constexpr size_t OFF_X    = OFF_BQKV + SZ_BQKV;
static constexpr size_t OFF_XB   = OFF_X + SZ_X;
static constexpr size_t OFF_QKV  = OFF_XB + SZ_ABF;
static constexpr size_t OFF_VT   = OFF_QKV + SZ_QKV;
static constexpr size_t OFF_OB   = OFF_VT + SZ_ABF;
static constexpr size_t OFF_H1   = OFF_QKV;  // FFN hidden aliases qkv+vt (dead then)

extern "C" void kernel_launch(void* const* d_in, const int* in_sizes, int n_in,
                              void* d_out, int out_size, void* d_ws, size_t ws_size,
                              hipStream_t stream) {
  const float* seq = (const float*)d_in[0];
  const float* wq = (const float*)d_in[1];  const float* bq = (const float*)d_in[2];
  const float* wk = (const float*)d_in[3];  const float* bk = (const float*)d_in[4];
  const float* wv = (const float*)d_in[5];  const float* bv = (const float*)d_in[6];
  const float* wo = (const float*)d_in[7];  const float* bo = (const float*)d_in[8];
  const float* w1 = (const float*)d_in[9];  const float* b1 = (const float*)d_in[10];
  const float* w2 = (const float*)d_in[11]; const float* b2 = (const float*)d_in[12];
  const float* g1 = (const float*)d_in[13]; const float* be1 = (const float*)d_in[14];
  const float* g2 = (const float*)d_in[15]; const float* be2 = (const float*)d_in[16];

  char* ws = (char*)d_ws;
  __bf16* wqkvt = (__bf16*)(ws + OFF_WQKVT);
  __bf16* wot = (__bf16*)(ws + OFF_WOT);
  __bf16* w1t = (__bf16*)(ws + OFF_W1T);
  __bf16* w2t = (__bf16*)(ws + OFF_W2T);
  float*  bqkv = (float*)(ws + OFF_BQKV);
  float*  xf  = (float*)(ws + OFF_X);
  __bf16* xb  = (__bf16*)(ws + OFF_XB);
  __bf16* qkvb = (__bf16*)(ws + OFF_QKV);
  __bf16* vtb = (__bf16*)(ws + OFF_VT);
  __bf16* ob  = (__bf16*)(ws + OFF_OB);
  __bf16* h1  = (__bf16*)(ws + OFF_H1);

  const size_t zDF = (size_t)DDIM * FFD;
  k_transpose_w4<<<dim3(16, 16, 16), 256, 0, stream>>>(wq, wk, wv, wo, wqkvt, wot);
  k_transpose_w<<<dim3(64, 16, LLN), 256, 0, stream>>>(w1, w1t, DDIM, FFD, zDF, zDF);
  k_transpose_w<<<dim3(16, 64, LLN), 256, 0, stream>>>(w2, w2t, FFD, DDIM, zDF, zDF);
  k_bias_fuse<<<LLN * NQKV / 256, 256, 0, stream>>>(bq, bk, bv, bqkv);
  k_cast<<<4096, 256, 0, stream>>>(seq, xf, xb);

  const int M = BB * SS;  // 8192
  for (int i = 0; i < LLN; ++i) {
    k_gemm256<3><<<dim3(NQKV / 256, M / 256), 512, 0, stream>>>(
        xb, wqkvt + (size_t)i * NQKV * DDIM, bqkv + i * NQKV, qkvb, M, NQKV, DDIM);
    k_transpose_v<<<dim3(SS / 32, DHD / 32, BB * HH), 256, 0, stream>>>(qkvb, vtb);
    k_attn<<<dim3(SS / 128, BB * HH), 256, 0, stream>>>(qkvb, vtb, ob);
    k_gemm_bt<2><<<dim3(DDIM / 64, M / 128), 256, 0, stream>>>(
        ob, wot + (size_t)i * DDIM * DDIM, bo + i * DDIM, xb, M, DDIM, DDIM,
        xf, xf, g1 + i * DDIM, be1 + i * DDIM);
    k_gemm256<1><<<dim3(FFD / 256, M / 256), 512, 0, stream>>>(
        xb, w1t + (size_t)i * DDIM * FFD, b1 + i * FFD, h1, M, FFD, DDIM);
    k_gemm_bt<2><<<dim3(DDIM / 64, M / 128), 256, 0, stream>>>(
        h1, w2t + (size_t)i * DDIM * FFD, b2 + i * DDIM, xb, M, DDIM, FFD,
        xf, (i == LLN - 1) ? (float*)d_out : xf, g2 + i * DDIM, be2 + i * DDIM);
  }
  (void)in_sizes; (void)n_in; (void)out_size; (void)ws_size;
}